// Round 10
// baseline (430.881 us; speedup 1.0000x reference)
//
#include <hip/hip_runtime.h>

typedef short short8 __attribute__((ext_vector_type(8)));
typedef float f32x4 __attribute__((ext_vector_type(4)));

#define N_NODES  50000
#define N_EDGES  800000
#define HID      128
#define EDGE_D   16
#define N_GRAPHS 64
#define KP1      288   // layer-1 K padded: 128 h_row + 128 h_col + 16 edge_attr + 1 radial + 15 pad

__device__ __forceinline__ float b2f(unsigned short u) {
    union { unsigned int i; float f; } v; v.i = ((unsigned int)u) << 16; return v.f;
}
__device__ __forceinline__ float u2f(unsigned int u) {
    union { unsigned int i; float f; } v; v.i = u; return v.f;
}
// round-half-up bf16 conversion: 2 VALU ops.
__device__ __forceinline__ unsigned short f2b(float f) {
    union { unsigned int i; float f; } v; v.f = f;
    return (unsigned short)((v.i + 0x8000u) >> 16);
}
// fast silu via rcp approx.
__device__ __forceinline__ float silu_f(float x) {
    return x * __builtin_amdgcn_rcpf(1.0f + __expf(-x));
}

__device__ __forceinline__ short8 cvt8(const float* __restrict__ p) {
    float4 f0 = *(const float4*)p;
    float4 f1 = *(const float4*)(p + 4);
    short8 r;
    r[0] = (short)f2b(f0.x); r[1] = (short)f2b(f0.y);
    r[2] = (short)f2b(f0.z); r[3] = (short)f2b(f0.w);
    r[4] = (short)f2b(f1.x); r[5] = (short)f2b(f1.y);
    r[6] = (short)f2b(f1.z); r[7] = (short)f2b(f1.w);
    return r;
}

// ---------------------------------------------------------------------------
// Prep: fp32->bf16 h + weights (transposed [N][K]); row histogram for sort.
// LESSON (r8): weights MUST go through LDS staging in the MLP kernels.
// ---------------------------------------------------------------------------
__global__ void prep_kernel(
    const float* __restrict__ We1, const float* __restrict__ We2,
    const float* __restrict__ Wn1, const float* __restrict__ Wn2,
    const float* __restrict__ h,
    const int* __restrict__ ei,
    unsigned short* __restrict__ We1T, unsigned short* __restrict__ We2T,
    unsigned short* __restrict__ Wn1T, unsigned short* __restrict__ Wn2T,
    unsigned short* __restrict__ h_bf16,
    int* __restrict__ hist)
{
    int stride = gridDim.x * blockDim.x;
    int i0 = blockIdx.x * blockDim.x + threadIdx.x;
    for (int t = i0; t < (N_NODES * HID) / 8; t += stride) {
        *(short8*)(h_bf16 + t * 8) = cvt8(h + t * 8);
    }
    for (int t = i0; t < N_EDGES; t += stride) {
        int r = min(max(ei[t], 0), N_NODES - 1);
        atomicAdd(&hist[r], 1);
    }
    for (int t = i0; t < 128 * KP1; t += stride) {
        int n = t / KP1, kp = t % KP1;
        float v = 0.f;
        int k;
        if (kp < 256) k = kp;
        else if (kp < 272) k = kp + 1;
        else if (kp == 272) k = 256;
        else k = -1;
        if (k >= 0) v = We1[k * HID + n];
        We1T[n * KP1 + kp] = f2b(v);
    }
    for (int t = i0; t < 128 * 128; t += stride) {
        int n = t >> 7, k = t & 127;
        We2T[n * HID + k] = f2b(We2[k * HID + n]);
        Wn2T[n * HID + k] = f2b(Wn2[k * HID + n]);
    }
    for (int t = i0; t < 128 * 256; t += stride) {
        int n = t >> 8, k = t & 255;
        Wn1T[n * 256 + k] = f2b(Wn1[k * HID + n]);
    }
}

// ---------------------------------------------------------------------------
// Two-level exclusive scan of the 50k row histogram (for counting sort).
// ---------------------------------------------------------------------------
__global__ void scan1_kernel(const int* __restrict__ hist, int* __restrict__ offs_local,
                             int* __restrict__ chunk_sums)
{
    __shared__ int buf[256];
    int tid = threadIdx.x, i = blockIdx.x * 256 + tid;
    int v = (i < N_NODES) ? hist[i] : 0;
    buf[tid] = v; __syncthreads();
    for (int off = 1; off < 256; off <<= 1) {
        int t = (tid >= off) ? buf[tid - off] : 0;
        __syncthreads();
        buf[tid] += t;
        __syncthreads();
    }
    if (i < N_NODES) offs_local[i] = buf[tid] - v;
    if (tid == 255) chunk_sums[blockIdx.x] = buf[255];
}

__global__ void scan2_kernel(const int* __restrict__ chunk_sums, int* __restrict__ blockpref)
{
    __shared__ int buf[256];
    int tid = threadIdx.x;
    int v = (tid < 196) ? chunk_sums[tid] : 0;
    buf[tid] = v; __syncthreads();
    for (int off = 1; off < 256; off <<= 1) {
        int t = (tid >= off) ? buf[tid - off] : 0;
        __syncthreads();
        buf[tid] += t;
        __syncthreads();
    }
    if (tid < 196) blockpref[tid] = buf[tid] - v;
}

__global__ void scatter_kernel(const int* __restrict__ ei,
                               const int* __restrict__ offs_local,
                               const int* __restrict__ blockpref,
                               int* __restrict__ cursor,
                               unsigned int* __restrict__ src_rc,
                               int* __restrict__ seid)
{
    int e = blockIdx.x * 256 + threadIdx.x;
    if (e < N_EDGES) {
        int r = min(max(ei[e], 0), N_NODES - 1);
        int c = min(max(ei[N_EDGES + e], 0), N_NODES - 1);
        int pos = blockpref[r >> 8] + offs_local[r] + atomicAdd(&cursor[r], 1);
        src_rc[pos] = ((unsigned int)r << 16) | (unsigned int)c;
        seid[pos] = e;
    }
}

// ---------------------------------------------------------------------------
// Edge MLP over ROW-SORTED edges: 512 thr, 256 edges/block, 2 m-tiles/wave.
// XCD swizzle: contiguous 1/8 slices of the sorted edge stream per XCD so
// row gathers stay in that XCD's 4MB L2 (row slice ~1.6MB).
// ---------------------------------------------------------------------------
#define EBLOCKS 3125          // N_EDGES / 256
#define ECHUNK  391           // ceil(EBLOCKS / 8)

__global__ __launch_bounds__(512, 4) void edge_kernel(
    const unsigned short* __restrict__ h,      // bf16
    const unsigned int* __restrict__ src_rc,
    const int* __restrict__ seid,
    const float* __restrict__ x,
    const float* __restrict__ ea,
    const unsigned short* __restrict__ We1T,
    const float* __restrict__ be1,
    const unsigned short* __restrict__ We2T,
    const float* __restrict__ be2,
    float* __restrict__ agg)
{
    __shared__ unsigned short efs[256 * 136];       // 69,632 B
    __shared__ unsigned short Wc[4 * 128 * 8];      //  8,192 B  [part][n][8]
    __shared__ unsigned short rowS[256];
    __shared__ unsigned short colS[256];
    __shared__ unsigned short radB[256];
    __shared__ unsigned short segS[256];
    __shared__ unsigned short segL[256];
    __shared__ int nsegL;

    const int bI  = (int)blockIdx.x;
    const int idx = (bI & 7) * ECHUNK + (bI >> 3);
    if (idx >= EBLOCKS) return;

    const int tid  = threadIdx.x;
    const int wave = tid >> 6;
    const int lane = tid & 63;
    const int quad = lane >> 4;
    const int l16  = lane & 15;
    const int e0   = idx * 256;

    if (tid == 0) nsegL = 0;
    if (tid < 256) {
        unsigned int rc = src_rc[e0 + tid];
        int r = rc >> 16;
        int c = rc & 0xffff;
        rowS[tid] = (unsigned short)r;
        colS[tid] = (unsigned short)c;
        float dx = x[r * 3 + 0] - x[c * 3 + 0];
        float dy = x[r * 3 + 1] - x[c * 3 + 1];
        float dz = x[r * 3 + 2] - x[c * 3 + 2];
        radB[tid] = f2b(dx * dx + dy * dy + dz * dz);
    }
    __syncthreads();

    if (tid < 256) {
        bool head = (tid == 0) || (rowS[tid] != rowS[tid - 1]);
        if (head) {
            int j = tid + 1;
            while (j < 256 && rowS[j] == rowS[tid]) ++j;
            int s = atomicAdd(&nsegL, 1);
            segS[s] = (unsigned short)tid;
            segL[s] = (unsigned short)(j - tid);
        }
    }

    const int m0 = wave * 32 + l16;
    const int m1 = m0 + 16;
    const int rA0 = rowS[m0], cA0 = colS[m0];
    const int rA1 = rowS[m1], cA1 = colS[m1];

    const int stg_n = tid >> 2, stg_p = tid & 3;
    unsigned short* stg_dst = Wc + stg_p * 1024 + stg_n * 8;

    const f32x4 fz = {0.f, 0.f, 0.f, 0.f};
    f32x4 acc0[8], acc1[8];
#pragma unroll
    for (int i = 0; i < 8; ++i) { acc0[i] = fz; acc1[i] = fz; }

    // ---- layer 1: K = 288 ----
    for (int kt = 0; kt < 9; ++kt) {
        __syncthreads();
        *(short8*)stg_dst = *(const short8*)(We1T + stg_n * KP1 + kt * 32 + stg_p * 8);
        short8 a0, a1;
        if (kt < 4) {
            a0 = *(const short8*)(h + rA0 * HID + kt * 32 + quad * 8);
            a1 = *(const short8*)(h + rA1 * HID + kt * 32 + quad * 8);
        } else if (kt < 8) {
            a0 = *(const short8*)(h + cA0 * HID + (kt - 4) * 32 + quad * 8);
            a1 = *(const short8*)(h + cA1 * HID + (kt - 4) * 32 + quad * 8);
        } else {
            short8 t0 = {0, 0, 0, 0, 0, 0, 0, 0}, t1 = t0;
            if (quad == 0) {
                t0 = cvt8(ea + (long)seid[e0 + m0] * EDGE_D);
                t1 = cvt8(ea + (long)seid[e0 + m1] * EDGE_D);
            } else if (quad == 1) {
                t0 = cvt8(ea + (long)seid[e0 + m0] * EDGE_D + 8);
                t1 = cvt8(ea + (long)seid[e0 + m1] * EDGE_D + 8);
            } else if (quad == 2) {
                t0[0] = (short)radB[m0];
                t1[0] = (short)radB[m1];
            }
            a0 = t0; a1 = t1;
        }
        __syncthreads();
#pragma unroll
        for (int nt = 0; nt < 8; ++nt) {
            short8 b = *(const short8*)(Wc + quad * 1024 + (nt * 16 + l16) * 8);
            acc0[nt] = __builtin_amdgcn_mfma_f32_16x16x32_bf16(a0, b, acc0[nt], 0, 0, 0);
            acc1[nt] = __builtin_amdgcn_mfma_f32_16x16x32_bf16(a1, b, acc1[nt], 0, 0, 0);
        }
    }

    // layer-1 epilogue: bias + silu -> efs (bf16)
#pragma unroll
    for (int nt = 0; nt < 8; ++nt) {
        float bias = be1[nt * 16 + l16];
#pragma unroll
        for (int r = 0; r < 4; ++r) {
            int mm = wave * 32 + quad * 4 + r;
            efs[mm * 136 + nt * 16 + l16]        = f2b(silu_f(acc0[nt][r] + bias));
            efs[(mm + 16) * 136 + nt * 16 + l16] = f2b(silu_f(acc1[nt][r] + bias));
        }
        acc0[nt] = fz; acc1[nt] = fz;
    }

    // ---- layer 2: K = 128 ----
    for (int kt = 0; kt < 4; ++kt) {
        __syncthreads();
        *(short8*)stg_dst = *(const short8*)(We2T + stg_n * HID + kt * 32 + stg_p * 8);
        __syncthreads();
        short8 a0 = *(const short8*)(efs + m0 * 136 + kt * 32 + quad * 8);
        short8 a1 = *(const short8*)(efs + m1 * 136 + kt * 32 + quad * 8);
#pragma unroll
        for (int nt = 0; nt < 8; ++nt) {
            short8 b = *(const short8*)(Wc + quad * 1024 + (nt * 16 + l16) * 8);
            acc0[nt] = __builtin_amdgcn_mfma_f32_16x16x32_bf16(a0, b, acc0[nt], 0, 0, 0);
            acc1[nt] = __builtin_amdgcn_mfma_f32_16x16x32_bf16(a1, b, acc1[nt], 0, 0, 0);
        }
    }

    // layer-2 epilogue: silu -> efs
#pragma unroll
    for (int nt = 0; nt < 8; ++nt) {
        float bias = be2[nt * 16 + l16];
#pragma unroll
        for (int r = 0; r < 4; ++r) {
            int mm = wave * 32 + quad * 4 + r;
            efs[mm * 136 + nt * 16 + l16]        = f2b(silu_f(acc0[nt][r] + bias));
            efs[(mm + 16) * 136 + nt * 16 + l16] = f2b(silu_f(acc1[nt][r] + bias));
        }
    }
    __syncthreads();

    // vectorized segmented reduce: 32 slots x 16 threads; integer bf16->f32
    const int slot = tid >> 4;
    const int sub  = tid & 15;
    for (int s = slot; s < nsegL; s += 32) {
        int st = segS[s], ln = segL[s];
        int row = rowS[st];
        f32x4 s0 = fz, s1 = fz;
        for (int i = 0; i < ln; ++i) {
            uint4 v = *(const uint4*)(efs + (st + i) * 136 + sub * 8);
            s0[0] += u2f(v.x << 16); s0[1] += u2f(v.x & 0xffff0000u);
            s0[2] += u2f(v.y << 16); s0[3] += u2f(v.y & 0xffff0000u);
            s1[0] += u2f(v.z << 16); s1[1] += u2f(v.z & 0xffff0000u);
            s1[2] += u2f(v.w << 16); s1[3] += u2f(v.w & 0xffff0000u);
        }
        float* dst = agg + row * HID + sub * 8;
        if (st == 0 || st + ln == 256) {
#pragma unroll
            for (int j = 0; j < 4; ++j) {
                atomicAdd(dst + j, s0[j]);
                atomicAdd(dst + 4 + j, s1[j]);
            }
        } else {
            *(f32x4*)dst = s0;
            *(f32x4*)(dst + 4) = s1;
        }
    }
}

// ---------------------------------------------------------------------------
// Node MLP + residual + block-reduced pooled-sum. 256 thr / 64 nodes per
// block (782 blocks): kills the 391-block tail quantization; LDS 26KB ->
// ~6 blocks/CU, 24 waves/CU (was 16).
// ---------------------------------------------------------------------------
__global__ __launch_bounds__(256, 8) void node_kernel(
    const unsigned short* __restrict__ hb,
    const float* __restrict__ hf,
    const float* __restrict__ agg,
    const int* __restrict__ batch,
    const unsigned short* __restrict__ Wn1T,
    const float* __restrict__ bn1,
    const unsigned short* __restrict__ Wn2T,
    const float* __restrict__ bn2,
    float* __restrict__ sums)
{
    __shared__ unsigned short efs[64 * 136];    // 17,408 B; reused as red[16][128]
    __shared__ unsigned short Wc[4 * 128 * 8];  //  8,192 B
    __shared__ int batchL[64];

    const int tid  = threadIdx.x;
    const int wave = tid >> 6;
    const int lane = tid & 63;
    const int quad = lane >> 4;
    const int l16  = lane & 15;
    const int n0   = blockIdx.x * 64;

    if (tid < 64) {
        int nd = min(n0 + tid, N_NODES - 1);
        batchL[tid] = min(max(batch[nd], 0), N_GRAPHS - 1);
    }
    __syncthreads();

    const int mA  = wave * 16 + l16;
    const int ndA = min(n0 + mA, N_NODES - 1);
    const int stg_n = tid >> 1, stg_p = tid & 1;   // 256 thr: 2x16B per thread per stage

    const f32x4 fz = {0.f, 0.f, 0.f, 0.f};
    f32x4 acc[8];
#pragma unroll
    for (int i = 0; i < 8; ++i) acc[i] = fz;

    for (int kt = 0; kt < 8; ++kt) {
        __syncthreads();
#pragma unroll
        for (int it = 0; it < 2; ++it) {
            int p = stg_p * 2 + it;
            *(short8*)(Wc + p * 1024 + stg_n * 8) =
                *(const short8*)(Wn1T + stg_n * 256 + kt * 32 + p * 8);
        }
        short8 a;
        if (kt < 4) a = *(const short8*)(hb + ndA * HID + kt * 32 + quad * 8);
        else        a = cvt8(agg + ndA * HID + (kt - 4) * 32 + quad * 8);
        __syncthreads();
#pragma unroll
        for (int nt = 0; nt < 8; ++nt) {
            short8 b = *(const short8*)(Wc + quad * 1024 + (nt * 16 + l16) * 8);
            acc[nt] = __builtin_amdgcn_mfma_f32_16x16x32_bf16(a, b, acc[nt], 0, 0, 0);
        }
    }

#pragma unroll
    for (int nt = 0; nt < 8; ++nt) {
        float bias = bn1[nt * 16 + l16];
#pragma unroll
        for (int r = 0; r < 4; ++r) {
            int mm = wave * 16 + quad * 4 + r;
            efs[mm * 136 + nt * 16 + l16] = f2b(silu_f(acc[nt][r] + bias));
        }
        acc[nt] = fz;
    }

    for (int kt = 0; kt < 4; ++kt) {
        __syncthreads();
#pragma unroll
        for (int it = 0; it < 2; ++it) {
            int p = stg_p * 2 + it;
            *(short8*)(Wc + p * 1024 + stg_n * 8) =
                *(const short8*)(Wn2T + stg_n * HID + kt * 32 + p * 8);
        }
        __syncthreads();
        short8 a = *(const short8*)(efs + mA * 136 + kt * 32 + quad * 8);
#pragma unroll
        for (int nt = 0; nt < 8; ++nt) {
            short8 b = *(const short8*)(Wc + quad * 1024 + (nt * 16 + l16) * 8);
            acc[nt] = __builtin_amdgcn_mfma_f32_16x16x32_bf16(a, b, acc[nt], 0, 0, 0);
        }
    }

    // ---- epilogue: bias + residual; two-graph block reduction ----
    float bias2[8];
#pragma unroll
    for (int nt = 0; nt < 8; ++nt) bias2[nt] = bn2[nt * 16 + l16];

    const int gA = batchL[0];
    const int gB = batchL[63];
    const int mbase = wave * 16 + quad * 4;
    float sA[8], sB[8];
#pragma unroll
    for (int nt = 0; nt < 8; ++nt) { sA[nt] = 0.f; sB[nt] = 0.f; }
#pragma unroll
    for (int r = 0; r < 4; ++r) {
        int mloc = mbase + r;
        int ndM = n0 + mloc;
        if (ndM < N_NODES) {
            int grp = batchL[mloc];
#pragma unroll
            for (int nt = 0; nt < 8; ++nt) {
                int nn = nt * 16 + l16;
                float hn = hf[ndM * HID + nn] + acc[nt][r] + bias2[nt];
                if (grp == gA)      sA[nt] += hn;
                else if (grp == gB) sB[nt] += hn;
                else atomicAdd(&sums[grp * HID + nn], hn);
            }
        }
    }

    __syncthreads();
    float* red = (float*)efs;              // [16][128]
    const int wq = wave * 4 + quad;        // 0..15
#pragma unroll
    for (int nt = 0; nt < 8; ++nt) red[wq * 128 + nt * 16 + l16] = sA[nt];
    __syncthreads();
    if (tid < 128) {
        float s = 0.f;
#pragma unroll
        for (int j = 0; j < 16; ++j) s += red[j * 128 + tid];
        atomicAdd(&sums[gA * HID + tid], s);
    }
    if (gB != gA) {
        __syncthreads();
#pragma unroll
        for (int nt = 0; nt < 8; ++nt) red[wq * 128 + nt * 16 + l16] = sB[nt];
        __syncthreads();
        if (tid < 128) {
            float s = 0.f;
#pragma unroll
            for (int j = 0; j < 16; ++j) s += red[j * 128 + tid];
            atomicAdd(&sums[gB * HID + tid], s);
        }
    }
}

// Per-graph counts via binary search over sorted batch (no atomics).
__global__ void final_kernel(const float* __restrict__ sums, const int* __restrict__ batch,
                             float* __restrict__ out) {
    __shared__ int cntS[2];
    const int b = blockIdx.x;
    const int tid = threadIdx.x;
    if (tid < 2) {
        int g = b * 2 + tid;
        int lo = 0, hi = N_NODES;
        while (lo < hi) { int mid = (lo + hi) >> 1; if (batch[mid] < g) lo = mid + 1; else hi = mid; }
        int s = lo;
        lo = 0; hi = N_NODES;
        while (lo < hi) { int mid = (lo + hi) >> 1; if (batch[mid] < g + 1) lo = mid + 1; else hi = mid; }
        cntS[tid] = lo - s;
    }
    __syncthreads();
    int i = b * 256 + tid;
    float c = fmaxf((float)cntS[tid >> 7], 1.0f);
    out[i] = sums[i] / c;
}

extern "C" void kernel_launch(void* const* d_in, const int* in_sizes, int n_in,
                              void* d_out, int out_size, void* d_ws, size_t ws_size,
                              hipStream_t stream)
{
    const float* h   = (const float*)d_in[0];
    const int*   ei  = (const int*)d_in[1];
    const float* x   = (const float*)d_in[2];
    const float* ea  = (const float*)d_in[3];
    const int*   bat = (const int*)d_in[4];
    const float* We1 = (const float*)d_in[5];
    const float* be1 = (const float*)d_in[6];
    const float* We2 = (const float*)d_in[7];
    const float* be2 = (const float*)d_in[8];
    const float* Wn1 = (const float*)d_in[9];
    const float* bn1 = (const float*)d_in[10];
    const float* Wn2 = (const float*)d_in[11];
    const float* bn2 = (const float*)d_in[12];

    char* ws = (char*)d_ws;
    unsigned short* We1T = (unsigned short*)(ws + 0);          //    73,728
    unsigned short* We2T = (unsigned short*)(ws + 73728);      //    32,768
    unsigned short* Wn1T = (unsigned short*)(ws + 106496);     //    65,536
    unsigned short* Wn2T = (unsigned short*)(ws + 172032);     //    32,768
    int*   offs_local    = (int*)(ws + 204800);                //   200,000
    int*   chunk_sums    = (int*)(ws + 404800);                //     1,024
    int*   blockpref     = (int*)(ws + 405824);                //     1,024
    unsigned int* src_rc = (unsigned int*)(ws + 406848);       // 3,200,000
    int*   seid          = (int*)(ws + 3606848);               // 3,200,000
    unsigned short* hb   = (unsigned short*)(ws + 6806848);    // 12,800,000
    // ---- zeroed region (contiguous) ----
    float* sums          = (float*)(ws + 19606848);            //    32,768
    int*   hist          = (int*)(ws + 19639616);              //   200,000
    int*   cursor        = (int*)(ws + 19839616);              //   200,000
    float* agg           = (float*)(ws + 20039616);            // 25,600,000 -> end 45,639,616

    hipMemsetAsync(ws + 19606848, 0, 26032768, stream);

    prep_kernel<<<512, 256, 0, stream>>>(We1, We2, Wn1, Wn2, h, ei,
                                         We1T, We2T, Wn1T, Wn2T, hb, hist);
    scan1_kernel<<<196, 256, 0, stream>>>(hist, offs_local, chunk_sums);
    scan2_kernel<<<1, 256, 0, stream>>>(chunk_sums, blockpref);
    scatter_kernel<<<(N_EDGES + 255) / 256, 256, 0, stream>>>(ei, offs_local, blockpref,
                                                              cursor, src_rc, seid);
    edge_kernel<<<8 * ECHUNK, 512, 0, stream>>>(hb, src_rc, seid, x, ea,
                                                We1T, be1, We2T, be2, agg);
    node_kernel<<<(N_NODES + 63) / 64, 256, 0, stream>>>(hb, h, agg, bat,
                                                         Wn1T, bn1, Wn2T, bn2, sums);
    final_kernel<<<N_GRAPHS / 2, 256, 0, stream>>>(sums, bat, (float*)d_out);
}

// Round 11
// 410.880 us; speedup vs baseline: 1.0487x; 1.0487x over previous
//
#include <hip/hip_runtime.h>

typedef short short8 __attribute__((ext_vector_type(8)));
typedef float f32x4 __attribute__((ext_vector_type(4)));

#define N_NODES  50000
#define N_EDGES  800000
#define HID      128
#define EDGE_D   16
#define N_GRAPHS 64
#define KP1      288   // layer-1 K padded: 128 h_row + 128 h_col + 16 edge_attr + 1 radial + 15 pad

__device__ __forceinline__ float b2f(unsigned short u) {
    union { unsigned int i; float f; } v; v.i = ((unsigned int)u) << 16; return v.f;
}
__device__ __forceinline__ float u2f(unsigned int u) {
    union { unsigned int i; float f; } v; v.i = u; return v.f;
}
// round-half-up bf16 conversion: 2 VALU ops.
__device__ __forceinline__ unsigned short f2b(float f) {
    union { unsigned int i; float f; } v; v.f = f;
    return (unsigned short)((v.i + 0x8000u) >> 16);
}
// fast silu via rcp approx.
__device__ __forceinline__ float silu_f(float x) {
    return x * __builtin_amdgcn_rcpf(1.0f + __expf(-x));
}

__device__ __forceinline__ short8 cvt8(const float* __restrict__ p) {
    float4 f0 = *(const float4*)p;
    float4 f1 = *(const float4*)(p + 4);
    short8 r;
    r[0] = (short)f2b(f0.x); r[1] = (short)f2b(f0.y);
    r[2] = (short)f2b(f0.z); r[3] = (short)f2b(f0.w);
    r[4] = (short)f2b(f1.x); r[5] = (short)f2b(f1.y);
    r[6] = (short)f2b(f1.z); r[7] = (short)f2b(f1.w);
    return r;
}

// ---------------------------------------------------------------------------
// Prep: fp32->bf16 h + weights (transposed [N][K]); row histogram for sort.
// LESSONS: (r8) weights must be LDS-staged in MLP kernels (sharing amplifier);
// (r10) don't shrink staging amortization for occupancy.
// ---------------------------------------------------------------------------
__global__ void prep_kernel(
    const float* __restrict__ We1, const float* __restrict__ We2,
    const float* __restrict__ Wn1, const float* __restrict__ Wn2,
    const float* __restrict__ h,
    const int* __restrict__ ei,
    unsigned short* __restrict__ We1T, unsigned short* __restrict__ We2T,
    unsigned short* __restrict__ Wn1T, unsigned short* __restrict__ Wn2T,
    unsigned short* __restrict__ h_bf16,
    int* __restrict__ hist)
{
    int stride = gridDim.x * blockDim.x;
    int i0 = blockIdx.x * blockDim.x + threadIdx.x;
    for (int t = i0; t < (N_NODES * HID) / 8; t += stride) {
        *(short8*)(h_bf16 + t * 8) = cvt8(h + t * 8);
    }
    for (int t = i0; t < N_EDGES; t += stride) {
        int r = min(max(ei[t], 0), N_NODES - 1);
        atomicAdd(&hist[r], 1);
    }
    for (int t = i0; t < 128 * KP1; t += stride) {
        int n = t / KP1, kp = t % KP1;
        float v = 0.f;
        int k;
        if (kp < 256) k = kp;
        else if (kp < 272) k = kp + 1;
        else if (kp == 272) k = 256;
        else k = -1;
        if (k >= 0) v = We1[k * HID + n];
        We1T[n * KP1 + kp] = f2b(v);
    }
    for (int t = i0; t < 128 * 128; t += stride) {
        int n = t >> 7, k = t & 127;
        We2T[n * HID + k] = f2b(We2[k * HID + n]);
        Wn2T[n * HID + k] = f2b(Wn2[k * HID + n]);
    }
    for (int t = i0; t < 128 * 256; t += stride) {
        int n = t >> 8, k = t & 255;
        Wn1T[n * 256 + k] = f2b(Wn1[k * HID + n]);
    }
}

// ---------------------------------------------------------------------------
// Two-level exclusive scan of the 50k row histogram (for counting sort).
// ---------------------------------------------------------------------------
__global__ void scan1_kernel(const int* __restrict__ hist, int* __restrict__ offs_local,
                             int* __restrict__ chunk_sums)
{
    __shared__ int buf[256];
    int tid = threadIdx.x, i = blockIdx.x * 256 + tid;
    int v = (i < N_NODES) ? hist[i] : 0;
    buf[tid] = v; __syncthreads();
    for (int off = 1; off < 256; off <<= 1) {
        int t = (tid >= off) ? buf[tid - off] : 0;
        __syncthreads();
        buf[tid] += t;
        __syncthreads();
    }
    if (i < N_NODES) offs_local[i] = buf[tid] - v;
    if (tid == 255) chunk_sums[blockIdx.x] = buf[255];
}

__global__ void scan2_kernel(const int* __restrict__ chunk_sums, int* __restrict__ blockpref)
{
    __shared__ int buf[256];
    int tid = threadIdx.x;
    int v = (tid < 196) ? chunk_sums[tid] : 0;
    buf[tid] = v; __syncthreads();
    for (int off = 1; off < 256; off <<= 1) {
        int t = (tid >= off) ? buf[tid - off] : 0;
        __syncthreads();
        buf[tid] += t;
        __syncthreads();
    }
    if (tid < 196) blockpref[tid] = buf[tid] - v;
}

// Counting-sort scatter; also precompute radial here (sorted bf16 srad[E])
// so edge setup reads it coalesced instead of 6 scattered x-gathers.
__global__ void scatter_kernel(const int* __restrict__ ei,
                               const float* __restrict__ x,
                               const int* __restrict__ offs_local,
                               const int* __restrict__ blockpref,
                               int* __restrict__ cursor,
                               unsigned int* __restrict__ src_rc,
                               int* __restrict__ seid,
                               unsigned short* __restrict__ srad)
{
    int e = blockIdx.x * 256 + threadIdx.x;
    if (e < N_EDGES) {
        int r = min(max(ei[e], 0), N_NODES - 1);
        int c = min(max(ei[N_EDGES + e], 0), N_NODES - 1);
        int pos = blockpref[r >> 8] + offs_local[r] + atomicAdd(&cursor[r], 1);
        src_rc[pos] = ((unsigned int)r << 16) | (unsigned int)c;
        seid[pos] = e;
        float dx = x[r * 3 + 0] - x[c * 3 + 0];
        float dy = x[r * 3 + 1] - x[c * 3 + 1];
        float dz = x[r * 3 + 2] - x[c * 3 + 2];
        srad[pos] = f2b(dx * dx + dy * dy + dz * dz);
    }
}

// ---------------------------------------------------------------------------
// Edge MLP over ROW-SORTED edges: 512 thr, 256 edges/block, 2 m-tiles/wave.
// LDS-staged weight chunks with REGISTER PREFETCH: kt+1's chunk is loaded
// into VGPRs during kt's MFMA phase, so the inter-barrier path is just a
// ds_write (was global-load ~200cyc + ds_write).
// ---------------------------------------------------------------------------
__global__ __launch_bounds__(512, 4) void edge_kernel(
    const unsigned short* __restrict__ h,      // bf16
    const unsigned int* __restrict__ src_rc,
    const int* __restrict__ seid,
    const unsigned short* __restrict__ srad,
    const float* __restrict__ ea,
    const unsigned short* __restrict__ We1T,
    const float* __restrict__ be1,
    const unsigned short* __restrict__ We2T,
    const float* __restrict__ be2,
    float* __restrict__ agg)
{
    __shared__ unsigned short efs[256 * 136];       // 69,632 B
    __shared__ unsigned short Wc[4 * 128 * 8];      //  8,192 B  [part][n][8]
    __shared__ unsigned short rowS[256];
    __shared__ unsigned short colS[256];
    __shared__ unsigned short radB[256];
    __shared__ unsigned short segS[256];
    __shared__ unsigned short segL[256];
    __shared__ int nsegL;

    const int tid  = threadIdx.x;
    const int wave = tid >> 6;
    const int lane = tid & 63;
    const int quad = lane >> 4;
    const int l16  = lane & 15;
    const int e0   = blockIdx.x * 256;

    if (tid == 0) nsegL = 0;
    if (tid < 256) {
        unsigned int rc = src_rc[e0 + tid];
        rowS[tid] = (unsigned short)(rc >> 16);
        colS[tid] = (unsigned short)(rc & 0xffff);
        radB[tid] = srad[e0 + tid];
    }
    __syncthreads();

    if (tid < 256) {
        bool head = (tid == 0) || (rowS[tid] != rowS[tid - 1]);
        if (head) {
            int j = tid + 1;
            while (j < 256 && rowS[j] == rowS[tid]) ++j;
            int s = atomicAdd(&nsegL, 1);
            segS[s] = (unsigned short)tid;
            segL[s] = (unsigned short)(j - tid);
        }
    }

    const int m0 = wave * 32 + l16;
    const int m1 = m0 + 16;
    const int rA0 = rowS[m0], cA0 = colS[m0];
    const int rA1 = rowS[m1], cA1 = colS[m1];

    const int stg_n = tid >> 2, stg_p = tid & 3;
    unsigned short* stg_dst = Wc + stg_p * 1024 + stg_n * 8;

    const f32x4 fz = {0.f, 0.f, 0.f, 0.f};
    f32x4 acc0[8], acc1[8];
#pragma unroll
    for (int i = 0; i < 8; ++i) { acc0[i] = fz; acc1[i] = fz; }

    // prefetch first weight chunk
    short8 wreg = *(const short8*)(We1T + stg_n * KP1 + stg_p * 8);

    // ---- layer 1: K = 288 ----
    for (int kt = 0; kt < 9; ++kt) {
        __syncthreads();
        *(short8*)stg_dst = wreg;
        // prefetch next chunk (layer-1 kt+1 or layer-2 kt=0)
        if (kt < 8) wreg = *(const short8*)(We1T + stg_n * KP1 + (kt + 1) * 32 + stg_p * 8);
        else        wreg = *(const short8*)(We2T + stg_n * HID + stg_p * 8);
        short8 a0, a1;
        if (kt < 4) {
            a0 = *(const short8*)(h + rA0 * HID + kt * 32 + quad * 8);
            a1 = *(const short8*)(h + rA1 * HID + kt * 32 + quad * 8);
        } else if (kt < 8) {
            a0 = *(const short8*)(h + cA0 * HID + (kt - 4) * 32 + quad * 8);
            a1 = *(const short8*)(h + cA1 * HID + (kt - 4) * 32 + quad * 8);
        } else {
            short8 t0 = {0, 0, 0, 0, 0, 0, 0, 0}, t1 = t0;
            if (quad == 0) {
                t0 = cvt8(ea + (long)seid[e0 + m0] * EDGE_D);
                t1 = cvt8(ea + (long)seid[e0 + m1] * EDGE_D);
            } else if (quad == 1) {
                t0 = cvt8(ea + (long)seid[e0 + m0] * EDGE_D + 8);
                t1 = cvt8(ea + (long)seid[e0 + m1] * EDGE_D + 8);
            } else if (quad == 2) {
                t0[0] = (short)radB[m0];
                t1[0] = (short)radB[m1];
            }
            a0 = t0; a1 = t1;
        }
        __syncthreads();
#pragma unroll
        for (int nt = 0; nt < 8; ++nt) {
            short8 b = *(const short8*)(Wc + quad * 1024 + (nt * 16 + l16) * 8);
            acc0[nt] = __builtin_amdgcn_mfma_f32_16x16x32_bf16(a0, b, acc0[nt], 0, 0, 0);
            acc1[nt] = __builtin_amdgcn_mfma_f32_16x16x32_bf16(a1, b, acc1[nt], 0, 0, 0);
        }
    }

    // layer-1 epilogue: bias + silu -> efs (bf16)
#pragma unroll
    for (int nt = 0; nt < 8; ++nt) {
        float bias = be1[nt * 16 + l16];
#pragma unroll
        for (int r = 0; r < 4; ++r) {
            int mm = wave * 32 + quad * 4 + r;
            efs[mm * 136 + nt * 16 + l16]        = f2b(silu_f(acc0[nt][r] + bias));
            efs[(mm + 16) * 136 + nt * 16 + l16] = f2b(silu_f(acc1[nt][r] + bias));
        }
        acc0[nt] = fz; acc1[nt] = fz;
    }

    // ---- layer 2: K = 128 ----
    for (int kt = 0; kt < 4; ++kt) {
        __syncthreads();
        *(short8*)stg_dst = wreg;
        if (kt < 3) wreg = *(const short8*)(We2T + stg_n * HID + (kt + 1) * 32 + stg_p * 8);
        __syncthreads();
        short8 a0 = *(const short8*)(efs + m0 * 136 + kt * 32 + quad * 8);
        short8 a1 = *(const short8*)(efs + m1 * 136 + kt * 32 + quad * 8);
#pragma unroll
        for (int nt = 0; nt < 8; ++nt) {
            short8 b = *(const short8*)(Wc + quad * 1024 + (nt * 16 + l16) * 8);
            acc0[nt] = __builtin_amdgcn_mfma_f32_16x16x32_bf16(a0, b, acc0[nt], 0, 0, 0);
            acc1[nt] = __builtin_amdgcn_mfma_f32_16x16x32_bf16(a1, b, acc1[nt], 0, 0, 0);
        }
    }

    // layer-2 epilogue: silu -> efs
#pragma unroll
    for (int nt = 0; nt < 8; ++nt) {
        float bias = be2[nt * 16 + l16];
#pragma unroll
        for (int r = 0; r < 4; ++r) {
            int mm = wave * 32 + quad * 4 + r;
            efs[mm * 136 + nt * 16 + l16]        = f2b(silu_f(acc0[nt][r] + bias));
            efs[(mm + 16) * 136 + nt * 16 + l16] = f2b(silu_f(acc1[nt][r] + bias));
        }
    }
    __syncthreads();

    // vectorized segmented reduce: 32 slots x 16 threads; integer bf16->f32
    const int slot = tid >> 4;
    const int sub  = tid & 15;
    for (int s = slot; s < nsegL; s += 32) {
        int st = segS[s], ln = segL[s];
        int row = rowS[st];
        f32x4 s0 = fz, s1 = fz;
        for (int i = 0; i < ln; ++i) {
            uint4 v = *(const uint4*)(efs + (st + i) * 136 + sub * 8);
            s0[0] += u2f(v.x << 16); s0[1] += u2f(v.x & 0xffff0000u);
            s0[2] += u2f(v.y << 16); s0[3] += u2f(v.y & 0xffff0000u);
            s1[0] += u2f(v.z << 16); s1[1] += u2f(v.z & 0xffff0000u);
            s1[2] += u2f(v.w << 16); s1[3] += u2f(v.w & 0xffff0000u);
        }
        float* dst = agg + row * HID + sub * 8;
        if (st == 0 || st + ln == 256) {
#pragma unroll
            for (int j = 0; j < 4; ++j) {
                atomicAdd(dst + j, s0[j]);
                atomicAdd(dst + 4 + j, s1[j]);
            }
        } else {
            *(f32x4*)dst = s0;
            *(f32x4*)(dst + 4) = s1;
        }
    }
}

// ---------------------------------------------------------------------------
// Node MLP + residual + block-reduced pooled-sum. 128 nodes / 512 thr
// (r10 lesson: smaller blocks double staging cost — net loss). Register
// weight prefetch as in edge_kernel.
// ---------------------------------------------------------------------------
__global__ __launch_bounds__(512, 4) void node_kernel(
    const unsigned short* __restrict__ hb,
    const float* __restrict__ hf,
    const float* __restrict__ agg,
    const int* __restrict__ batch,
    const unsigned short* __restrict__ Wn1T,
    const float* __restrict__ bn1,
    const unsigned short* __restrict__ Wn2T,
    const float* __restrict__ bn2,
    float* __restrict__ sums)
{
    __shared__ unsigned short efs[128 * 136];   // reused as float red[32][128]
    __shared__ unsigned short Wc[4 * 128 * 8];
    __shared__ int batchL[128];

    const int tid  = threadIdx.x;
    const int wave = tid >> 6;
    const int lane = tid & 63;
    const int quad = lane >> 4;
    const int l16  = lane & 15;
    const int n0   = blockIdx.x * 128;

    if (tid < 128) {
        int nd = min(n0 + tid, N_NODES - 1);
        batchL[tid] = min(max(batch[nd], 0), N_GRAPHS - 1);
    }
    __syncthreads();

    const int mA  = wave * 16 + l16;
    const int ndA = min(n0 + mA, N_NODES - 1);
    const int stg_n = tid >> 2, stg_p = tid & 3;
    unsigned short* stg_dst = Wc + stg_p * 1024 + stg_n * 8;

    const f32x4 fz = {0.f, 0.f, 0.f, 0.f};
    f32x4 acc[8];
#pragma unroll
    for (int i = 0; i < 8; ++i) acc[i] = fz;

    short8 wreg = *(const short8*)(Wn1T + stg_n * 256 + stg_p * 8);

    for (int kt = 0; kt < 8; ++kt) {
        __syncthreads();
        *(short8*)stg_dst = wreg;
        if (kt < 7) wreg = *(const short8*)(Wn1T + stg_n * 256 + (kt + 1) * 32 + stg_p * 8);
        else        wreg = *(const short8*)(Wn2T + stg_n * HID + stg_p * 8);
        short8 a;
        if (kt < 4) a = *(const short8*)(hb + ndA * HID + kt * 32 + quad * 8);
        else        a = cvt8(agg + ndA * HID + (kt - 4) * 32 + quad * 8);
        __syncthreads();
#pragma unroll
        for (int nt = 0; nt < 8; ++nt) {
            short8 b = *(const short8*)(Wc + quad * 1024 + (nt * 16 + l16) * 8);
            acc[nt] = __builtin_amdgcn_mfma_f32_16x16x32_bf16(a, b, acc[nt], 0, 0, 0);
        }
    }

#pragma unroll
    for (int nt = 0; nt < 8; ++nt) {
        float bias = bn1[nt * 16 + l16];
#pragma unroll
        for (int r = 0; r < 4; ++r) {
            int mm = wave * 16 + quad * 4 + r;
            efs[mm * 136 + nt * 16 + l16] = f2b(silu_f(acc[nt][r] + bias));
        }
        acc[nt] = fz;
    }

    for (int kt = 0; kt < 4; ++kt) {
        __syncthreads();
        *(short8*)stg_dst = wreg;
        if (kt < 3) wreg = *(const short8*)(Wn2T + stg_n * HID + (kt + 1) * 32 + stg_p * 8);
        __syncthreads();
        short8 a = *(const short8*)(efs + mA * 136 + kt * 32 + quad * 8);
#pragma unroll
        for (int nt = 0; nt < 8; ++nt) {
            short8 b = *(const short8*)(Wc + quad * 1024 + (nt * 16 + l16) * 8);
            acc[nt] = __builtin_amdgcn_mfma_f32_16x16x32_bf16(a, b, acc[nt], 0, 0, 0);
        }
    }

    // ---- epilogue: bias + residual; two-graph block reduction ----
    float bias2[8];
#pragma unroll
    for (int nt = 0; nt < 8; ++nt) bias2[nt] = bn2[nt * 16 + l16];

    const int gA = batchL[0];
    const int gB = batchL[127];
    const int mbase = wave * 16 + quad * 4;
    float sA[8], sB[8];
#pragma unroll
    for (int nt = 0; nt < 8; ++nt) { sA[nt] = 0.f; sB[nt] = 0.f; }
#pragma unroll
    for (int r = 0; r < 4; ++r) {
        int mloc = mbase + r;
        int ndM = n0 + mloc;
        if (ndM < N_NODES) {
            int grp = batchL[mloc];
#pragma unroll
            for (int nt = 0; nt < 8; ++nt) {
                int nn = nt * 16 + l16;
                float hn = hf[ndM * HID + nn] + acc[nt][r] + bias2[nt];
                if (grp == gA)      sA[nt] += hn;
                else if (grp == gB) sB[nt] += hn;
                else atomicAdd(&sums[grp * HID + nn], hn);
            }
        }
    }

    __syncthreads();
    float* red = (float*)efs;              // [32][128]
    const int wq = wave * 4 + quad;
#pragma unroll
    for (int nt = 0; nt < 8; ++nt) red[wq * 128 + nt * 16 + l16] = sA[nt];
    __syncthreads();
    if (tid < 128) {
        float s = 0.f;
#pragma unroll
        for (int j = 0; j < 32; ++j) s += red[j * 128 + tid];
        atomicAdd(&sums[gA * HID + tid], s);
    }
    if (gB != gA) {
        __syncthreads();
#pragma unroll
        for (int nt = 0; nt < 8; ++nt) red[wq * 128 + nt * 16 + l16] = sB[nt];
        __syncthreads();
        if (tid < 128) {
            float s = 0.f;
#pragma unroll
            for (int j = 0; j < 32; ++j) s += red[j * 128 + tid];
            atomicAdd(&sums[gB * HID + tid], s);
        }
    }
}

// Per-graph counts via binary search over sorted batch (no atomics).
__global__ void final_kernel(const float* __restrict__ sums, const int* __restrict__ batch,
                             float* __restrict__ out) {
    __shared__ int cntS[2];
    const int b = blockIdx.x;
    const int tid = threadIdx.x;
    if (tid < 2) {
        int g = b * 2 + tid;
        int lo = 0, hi = N_NODES;
        while (lo < hi) { int mid = (lo + hi) >> 1; if (batch[mid] < g) lo = mid + 1; else hi = mid; }
        int s = lo;
        lo = 0; hi = N_NODES;
        while (lo < hi) { int mid = (lo + hi) >> 1; if (batch[mid] < g + 1) lo = mid + 1; else hi = mid; }
        cntS[tid] = lo - s;
    }
    __syncthreads();
    int i = b * 256 + tid;
    float c = fmaxf((float)cntS[tid >> 7], 1.0f);
    out[i] = sums[i] / c;
}

extern "C" void kernel_launch(void* const* d_in, const int* in_sizes, int n_in,
                              void* d_out, int out_size, void* d_ws, size_t ws_size,
                              hipStream_t stream)
{
    const float* h   = (const float*)d_in[0];
    const int*   ei  = (const int*)d_in[1];
    const float* x   = (const float*)d_in[2];
    const float* ea  = (const float*)d_in[3];
    const int*   bat = (const int*)d_in[4];
    const float* We1 = (const float*)d_in[5];
    const float* be1 = (const float*)d_in[6];
    const float* We2 = (const float*)d_in[7];
    const float* be2 = (const float*)d_in[8];
    const float* Wn1 = (const float*)d_in[9];
    const float* bn1 = (const float*)d_in[10];
    const float* Wn2 = (const float*)d_in[11];
    const float* bn2 = (const float*)d_in[12];

    char* ws = (char*)d_ws;
    unsigned short* We1T = (unsigned short*)(ws + 0);          //    73,728
    unsigned short* We2T = (unsigned short*)(ws + 73728);      //    32,768
    unsigned short* Wn1T = (unsigned short*)(ws + 106496);     //    65,536
    unsigned short* Wn2T = (unsigned short*)(ws + 172032);     //    32,768
    int*   offs_local    = (int*)(ws + 204800);                //   200,000
    int*   chunk_sums    = (int*)(ws + 404800);                //     1,024
    int*   blockpref     = (int*)(ws + 405824);                //     1,024
    unsigned int* src_rc = (unsigned int*)(ws + 406848);       // 3,200,000
    int*   seid          = (int*)(ws + 3606848);               // 3,200,000
    unsigned short* srad = (unsigned short*)(ws + 6806848);    // 1,600,000
    unsigned short* hb   = (unsigned short*)(ws + 8406848);    // 12,800,000
    // ---- zeroed region (contiguous) ----
    float* sums          = (float*)(ws + 21206848);            //    32,768
    int*   hist          = (int*)(ws + 21239616);              //   200,000
    int*   cursor        = (int*)(ws + 21439616);              //   200,000
    float* agg           = (float*)(ws + 21639616);            // 25,600,000 -> end 47,239,616

    hipMemsetAsync(ws + 21206848, 0, 26032768, stream);

    prep_kernel<<<512, 256, 0, stream>>>(We1, We2, Wn1, Wn2, h, ei,
                                         We1T, We2T, Wn1T, Wn2T, hb, hist);
    scan1_kernel<<<196, 256, 0, stream>>>(hist, offs_local, chunk_sums);
    scan2_kernel<<<1, 256, 0, stream>>>(chunk_sums, blockpref);
    scatter_kernel<<<(N_EDGES + 255) / 256, 256, 0, stream>>>(ei, x, offs_local, blockpref,
                                                              cursor, src_rc, seid, srad);
    edge_kernel<<<N_EDGES / 256, 512, 0, stream>>>(hb, src_rc, seid, srad, ea,
                                                   We1T, be1, We2T, be2, agg);
    node_kernel<<<(N_NODES + 127) / 128, 512, 0, stream>>>(hb, h, agg, bat,
                                                           Wn1T, bn1, Wn2T, bn2, sums);
    final_kernel<<<N_GRAPHS / 2, 256, 0, stream>>>(sums, bat, (float*)d_out);
}